// Round 16
// baseline (169.009 us; speedup 1.0000x reference)
//
#include <hip/hip_runtime.h>

typedef unsigned short u16;
typedef unsigned int u32;
typedef unsigned long long u64;
typedef __bf16 bf16x8 __attribute__((ext_vector_type(8)));
typedef float f32x4 __attribute__((ext_vector_type(4)));

#define MFMA16(a, b, c) __builtin_amdgcn_mfma_f32_16x16x32_bf16(a, b, c, 0, 0, 0)

static __device__ __forceinline__ u16 f2bf(float f) {
  union { float f; u32 u; } v; v.f = f;
  u32 u = v.u;
  u32 r = (u + 0x7FFFu + ((u >> 16) & 1u)) >> 16;  // RNE
  return (u16)r;
}

static __device__ __forceinline__ bf16x8 ld16(const u16* p) {
  return __builtin_bit_cast(bf16x8, *(const uint4*)p);
}

static __device__ __forceinline__ u64 u64min(u64 a, u64 b) { return a < b ? a : b; }

// In-wave bitonic sort of 64 u64 keys, ascending by lane.
static __device__ __forceinline__ u64 bitonic64(u64 v, int lane) {
#pragma unroll
  for (int k = 2; k <= 64; k <<= 1) {
#pragma unroll
    for (int j = k >> 1; j > 0; j >>= 1) {
      u64 o = __shfl_xor(v, j, 64);
      bool up = ((lane & k) == 0);
      bool lower = ((lane & j) == 0);
      u64 mn = v < o ? v : o;
      u64 mx = v < o ? o : v;
      v = (lower == up) ? mn : mx;
    }
  }
  return v;
}

// In-wave bitonic sort of 64 f32 (no NaN), ascending by lane.
static __device__ __forceinline__ float bitonic64f(float v, int lane) {
#pragma unroll
  for (int k = 2; k <= 64; k <<= 1) {
#pragma unroll
    for (int j = k >> 1; j > 0; j >>= 1) {
      float o = __shfl_xor(v, j, 64);
      bool up = ((lane & k) == 0);
      bool lower = ((lane & j) == 0);
      float mn = fminf(v, o);
      float mx = fmaxf(v, o);
      v = (lower == up) ? mn : mx;
    }
  }
  return v;
}

// monotone u32 key from f32 bits — pure integer transform (safe to duplicate)
static __device__ __forceinline__ u32 fkey(float f) {
  u32 bb = __float_as_uint(f);
  u32 sgn = (u32)((int)bb >> 31);
  return bb ^ (sgn | 0x80000000u);
}

// Reference fp32 distance semantics (matches np, verified r3..r15):
//   dot = fma(z,bz, fma(y,by, mul(x,bx)));  d2 = fl(fl(s1+s2) - fl(2*dot))
static __device__ __forceinline__ float d2of(float x, float y, float z, float s1,
                                             f32x4 c) {
  float dt = __builtin_fmaf(z, c[2], __builtin_fmaf(y, c[1], __fmul_rn(x, c[0])));
  return __fsub_rn(__fadd_rn(s1, c[3]), __fmul_rn(2.0f, dt));
}

// ---------------------------------------------------------------------------
// K1: PREP + KNN-16 in one kernel (verbatim r15 — measured 58.7 µs; r12
// lesson: this shape sits just under LDS/VGPR cliffs, do not add pressure).
// ---------------------------------------------------------------------------
__global__ __launch_bounds__(256, 2) void knn_prep(
    const float* __restrict__ xyz1, const float* __restrict__ xyz2,
    const float* __restrict__ points1, const float* __restrict__ points2,
    const float* __restrict__ W1, const float* __restrict__ W2,
    u16* __restrict__ p1t, u16* __restrict__ p2t,
    u16* __restrict__ W1b, u16* __restrict__ W2b,
    int* __restrict__ knn) {
  __shared__ __align__(16) char LB[65536];
  f32x4* candL = (f32x4*)LB;     // 4096 * 16 B (knn phase)
  u16* tile = (u16*)LB;          // 64*66*2 = 8448 B (transpose phase)
  __shared__ u64 surv[4][64];    // 2 KB
  __shared__ u32 cnt[4];
  const int t = threadIdx.x;
  const int lane = t & 63;
  const int w = t >> 6;
  const int g = blockIdx.x;

  // ---- part 0: W cast (blocks 0..143) ------------------------------------
  if (g < 144) {
    int i = g * 256 + t;
    if (i < 128 * 160) {
      int r = i / 160, c = i - r * 160;
      W1b[i] = (c < 131) ? f2bf(W1[r * 131 + c]) : (u16)0;
    } else {
      int u = i - 128 * 160;
      W2b[u] = f2bf(W2[u]);
    }
  }

  // ---- part 1: one transpose tile per block ------------------------------
  {
    const float* src = (g < 256) ? points1 : points2;
    u16* dst = (g < 256) ? p1t : p2t;
    const int gb = g & 255;
    const int tb = gb >> 6;
    const int n0 = (gb & 63) << 6;
    const float* sp = src + ((size_t)tb << 18);
#pragma unroll
    for (int i = 0; i < 16; i++) {
      int d = (i << 2) + (t >> 6);
      int n = t & 63;
      tile[n * 66 + d] = f2bf(sp[((size_t)d << 12) + n0 + n]);
    }
    __syncthreads();
    u16* dp = dst + ((size_t)(tb * 4096 + n0) << 6);
#pragma unroll
    for (int i = 0; i < 8; i++) {
      int n = (i << 3) + (t >> 5);
      int dp2 = t & 31;
      *(u32*)(dp + n * 64 + (dp2 << 1)) = *(const u32*)(tile + n * 66 + (dp2 << 1));
    }
  }
  __syncthreads();  // tile reads complete before candL overwrites the region

  // ---- part 2: stage candidates; SINGLE site computing s2 (r5 lesson) ----
  const int b = g >> 7;              // 512 blocks: 128 per batch
  const int rbase = (g & 127) << 5;  // 32 rows per block
  const float* X1 = xyz1 + b * 12288;
  const float* X2 = xyz2 + b * 12288;
#pragma unroll
  for (int i = 0; i < 16; i++) {
    int m = i * 256 + t;
    float x = X2[m], y = X2[4096 + m], z = X2[8192 + m];
    float s2 = __fadd_rn(__fadd_rn(__fmul_rn(x, x), __fmul_rn(y, y)),
                         __fmul_rn(z, z));
    f32x4 pk = {x, y, z, s2};
    candL[m] = pk;
  }
  __syncthreads();

  // ---- part 3: KNN (verbatim r13; keys[64] ONE array — r4/r10 lesson) ----
#pragma unroll 1
  for (int r = 0; r < 8; r++) {
    const int n = rbase + (w << 3) + r;
    const int row = b * 4096 + n;
    const float x = X1[n], y = X1[4096 + n], z = X1[8192 + n];
    const float s1 = __fadd_rn(__fadd_rn(__fmul_rn(x, x), __fmul_rn(y, y)),
                               __fmul_rn(z, z));

    float keys[64];
    float fm = 3e38f;
#pragma unroll
    for (int j = 0; j < 64; j++) {
      const int m = (j << 6) + lane;
      f32x4 c = candL[m];
      float d = d2of(x, y, z, s1, c);
      keys[j] = d;
      fm = fminf(fm, d);
    }

    float tauf = __shfl(bitonic64f(fm, lane), 15, 64);

    if (lane == 0) cnt[w] = 0;
#pragma unroll
    for (int j = 0; j < 64; j++) {
      if (keys[j] <= tauf) {
        u64 k64 = ((u64)fkey(keys[j]) << 32) | (u32)((j << 6) + lane);
        u32 slot = atomicAdd(&cnt[w], 1u);
        if (slot < 64) surv[w][slot] = k64;
      }
    }
    u32 S = cnt[w];  // same-wave LDS ops in program order

    if (S <= 64) {
      u64 v = (lane < (int)S) ? surv[w][lane] : ~0ull;
      v = bitonic64(v, lane);
      if (lane < 16) knn[row * 16 + lane] = (int)(v & 0xFFFFFFFFull);
    } else {
      // exact cold path: increasing-order extraction from the register keys
      u64 prev = 0;
      for (int rr = 0; rr < 16; rr++) {
        u64 lm = ~0ull;
#pragma unroll
        for (int j = 0; j < 64; j++) {
          u64 k64 = ((u64)fkey(keys[j]) << 32) | (u32)((j << 6) + lane);
          if (k64 > prev && k64 < lm) lm = k64;
        }
        u64 gm = lm;
#pragma unroll
        for (int off = 32; off; off >>= 1) gm = u64min(gm, __shfl_xor(gm, off, 64));
        if (lane == 0) knn[row * 16 + rr] = (int)(gm & 0xFFFFFFFFull);
        prev = gm;
      }
    }
  }
}

// ---------------------------------------------------------------------------
// K3: fused gather + MLP + weighted reduce.  ROUND 16: 2x2 wave tiling —
// wave w -> (m-half = w>>1: 64 rows, n-half = w&1: 64 channels).  Halves the
// redundant F/H1 LDS reads vs the r9 N-split (288 -> 144 ds_read_b128 per
// block) — LDS is mlp's dominant pipe.  Per-output-element MFMA K-order is
// unchanged -> output bit-identical.  W working set per block is 72 KB
// (L2-served, ~147 MB device-wide ≈ 4 µs — acceptable; r8's 600 MB disease
// was per-lane L2 latency at low occupancy, not present at 12 waves/CU).
// ---------------------------------------------------------------------------
__global__ __launch_bounds__(256, 3) void mlp_kernel(
    const float* __restrict__ xyz1, const float* __restrict__ xyz2,
    const u16* __restrict__ p1t, const u16* __restrict__ p2t,
    const int* __restrict__ knn,
    const u16* __restrict__ W1b, const float* __restrict__ b1,
    const u16* __restrict__ W2b, const float* __restrict__ b2,
    float* __restrict__ out) {
  __shared__ __align__(16) u16 F[128 * 168];
  __shared__ __align__(16) float winv[128];
  __shared__ __align__(16) float wnorm[128];
  __shared__ __align__(16) float outbuf[128 * 12];
  const int t = threadIdx.x;
  const int g = blockIdx.x;
  const int b = g >> 9;
  const int rbase = (g & 511) << 3;

  // ---- Phase A: build F = [p1 | p2[idx] | dir | 0-pad] --------------------
  {
    const int m = t >> 1, half = t & 1;
    const int n1 = rbase + (m >> 4);
    const uint4* s1p = (const uint4*)(p1t + ((size_t)(b * 4096 + n1) << 6)) + half * 4;
    uint4* d1p = (uint4*)(F + m * 168) + half * 4;
    d1p[0] = s1p[0]; d1p[1] = s1p[1]; d1p[2] = s1p[2]; d1p[3] = s1p[3];
    const int idx = knn[(((size_t)(b * 4096 + n1)) << 4) + (m & 15)];
    const uint4* s2p = (const uint4*)(p2t + ((size_t)(b * 4096 + idx) << 6)) + half * 4;
    uint4* d2p = (uint4*)(F + m * 168 + 64) + half * 4;
    d2p[0] = s2p[0]; d2p[1] = s2p[1]; d2p[2] = s2p[2]; d2p[3] = s2p[3];
  }
  if (t < 128) {
    const int m = t;
    const int n1 = rbase + (m >> 4);
    const int idx = knn[(((size_t)(b * 4096 + n1)) << 4) + (m & 15)];
    const float* X1 = xyz1 + b * 12288;
    const float* X2 = xyz2 + b * 12288;
    float dx = X2[idx] - X1[n1];
    float dy = X2[4096 + idx] - X1[4096 + n1];
    float dz = X2[8192 + idx] - X1[8192 + n1];
    u32 u0 = (u32)f2bf(dx) | ((u32)f2bf(dy) << 16);
    u32 u1 = (u32)f2bf(dz);
    uint4 pk = make_uint4(u0, u1, 0u, 0u);
    *(uint4*)(F + m * 168 + 128) = pk;
    float d = sqrtf(dx * dx + dy * dy + dz * dz);
    winv[m] = 1.0f / fmaxf(d, 1e-10f);
  } else {
    const int m = t - 128;
    uint4 zz = make_uint4(0u, 0u, 0u, 0u);
    uint4* zp = (uint4*)(F + m * 168 + 136);
    zp[0] = zz; zp[1] = zz; zp[2] = zz; zp[3] = zz;
  }
  __syncthreads();  // barrier 1: F + winv visible

  if (t < 128) {
    const int r = t >> 4;
    float s = 0.f;
#pragma unroll
    for (int k = 0; k < 16; k++) s += winv[(r << 4) + k];
    wnorm[t] = winv[t] / s;
  }

  const int lane = t & 63;
  const int wid = t >> 6;
  const int l15 = lane & 15;
  const int quad = lane >> 4;
  const int koff = quad << 3;
  const int mh = wid >> 1;       // m-half: rows mbase..mbase+63
  const int nh = wid & 1;        // n-half: channels nbase..nbase+63
  const int mbase = mh << 6;
  const int nbase = nh << 6;

  // ---- GEMM1: 4 m-tiles x 4 n-tiles, K=160 -------------------------------
  f32x4 acc[4][4];
  const f32x4 z4 = {0.f, 0.f, 0.f, 0.f};
#pragma unroll
  for (int i = 0; i < 4; i++)
#pragma unroll
    for (int j = 0; j < 4; j++) acc[i][j] = z4;

#pragma unroll
  for (int s = 0; s < 5; s++) {
    bf16x8 bf[4];
#pragma unroll
    for (int nt = 0; nt < 4; nt++)
      bf[nt] = ld16(W1b + (nbase + nt * 16 + l15) * 160 + s * 32 + koff);
#pragma unroll
    for (int mt = 0; mt < 4; mt++) {
      bf16x8 a = ld16(F + (mbase + mt * 16 + l15) * 168 + s * 32 + koff);
#pragma unroll
      for (int nt = 0; nt < 4; nt++)
        acc[mt][nt] = MFMA16(a, bf[nt], acc[mt][nt]);
    }
  }
  __syncthreads();  // barrier 2: GEMM1 reads done before H1 overwrite

  // H1 = leaky(acc + b1) -> F rows mbase.., cols nbase.. (4 waves tile H1)
#pragma unroll
  for (int mt = 0; mt < 4; mt++) {
    u16* hrow = F + (mbase + mt * 16 + quad * 4) * 168;
#pragma unroll
    for (int nt = 0; nt < 4; nt++) {
      const float bv = b1[nbase + nt * 16 + l15];
#pragma unroll
      for (int r = 0; r < 4; r++) {
        float zv = acc[mt][nt][r] + bv;
        zv = (zv >= 0.f) ? zv : 0.1f * zv;
        hrow[r * 168 + nbase + nt * 16 + l15] = f2bf(zv);
      }
    }
  }
  __syncthreads();  // barrier 3: H1 visible

  // ---- GEMM2: rows mbase.. x channels nbase.., K=128 ---------------------
  f32x4 acc2[4][4];
#pragma unroll
  for (int i = 0; i < 4; i++)
#pragma unroll
    for (int j = 0; j < 4; j++) acc2[i][j] = z4;

#pragma unroll
  for (int s = 0; s < 4; s++) {
    bf16x8 bf[4];
#pragma unroll
    for (int nt = 0; nt < 4; nt++)
      bf[nt] = ld16(W2b + (nbase + nt * 16 + l15) * 128 + s * 32 + koff);
#pragma unroll
    for (int mt = 0; mt < 4; mt++) {
      bf16x8 a = ld16(F + (mbase + mt * 16 + l15) * 168 + s * 32 + koff);
#pragma unroll
      for (int nt = 0; nt < 4; nt++)
        acc2[mt][nt] = MFMA16(a, bf[nt], acc2[mt][nt]);
    }
  }

  // ---- epilogue: leaky + bias, weighted sum over k -----------------------
#pragma unroll
  for (int mt = 0; mt < 4; mt++) {
    const int mrow = (mh << 2) + mt;  // local query row 0..7
    const f32x4 w4 = *(const f32x4*)&wnorm[(mrow << 4) + (quad << 2)];
#pragma unroll
    for (int nt = 0; nt < 4; nt++) {
      const float bv = b2[nbase + nt * 16 + l15];
      float p = 0.f;
#pragma unroll
      for (int r = 0; r < 4; r++) {
        float zv = acc2[mt][nt][r] + bv;
        zv = (zv >= 0.f) ? zv : 0.1f * zv;
        p += zv * w4[r];
      }
      p += __shfl_xor(p, 16);
      p += __shfl_xor(p, 32);
      if (quad == 0) outbuf[(nbase + nt * 16 + l15) * 12 + mrow] = p;
    }
  }
  __syncthreads();  // barrier 4: outbuf visible
  {
    const int ch = t >> 1, half = t & 1;
    f32x4 v = *(const f32x4*)&outbuf[ch * 12 + (half << 2)];
    float* op = out + (((size_t)(b * 128 + ch)) << 12) + rbase + (half << 2);
    *(f32x4*)op = v;
  }
}

// ---------------------------------------------------------------------------
extern "C" void kernel_launch(void* const* d_in, const int* in_sizes, int n_in,
                              void* d_out, int out_size, void* d_ws, size_t ws_size,
                              hipStream_t stream) {
  const float* xyz1 = (const float*)d_in[0];
  const float* xyz2 = (const float*)d_in[1];
  const float* points1 = (const float*)d_in[2];
  const float* points2 = (const float*)d_in[3];
  const float* W1 = (const float*)d_in[4];
  const float* b1 = (const float*)d_in[5];
  const float* W2 = (const float*)d_in[6];
  const float* b2 = (const float*)d_in[7];
  float* out = (float*)d_out;

  char* ws = (char*)d_ws;
  int* knn = (int*)ws;                        // 1,048,576 B
  u16* p1t = (u16*)(ws + 1048576);            // 2,097,152 B
  u16* p2t = (u16*)(ws + 3145728);            // 2,097,152 B
  u16* W1b = (u16*)(ws + 5242880);            // 40,960 B
  u16* W2b = (u16*)(ws + 5283840);            // 32,768 B

  hipLaunchKernelGGL(knn_prep, dim3(512), dim3(256), 0, stream,
                     xyz1, xyz2, points1, points2, W1, W2, p1t, p2t, W1b, W2b, knn);
  hipLaunchKernelGGL(mlp_kernel, dim3(2048), dim3(256), 0, stream,
                     xyz1, xyz2, p1t, p2t, knn, W1b, b1, W2b, b2, out);
}

// Round 17
// 157.895 us; speedup vs baseline: 1.0704x; 1.0704x over previous
//
#include <hip/hip_runtime.h>

typedef unsigned short u16;
typedef unsigned int u32;
typedef unsigned long long u64;
typedef __bf16 bf16x8 __attribute__((ext_vector_type(8)));
typedef float f32x4 __attribute__((ext_vector_type(4)));

#define MFMA16(a, b, c) __builtin_amdgcn_mfma_f32_16x16x32_bf16(a, b, c, 0, 0, 0)

static __device__ __forceinline__ u16 f2bf(float f) {
  union { float f; u32 u; } v; v.f = f;
  u32 u = v.u;
  u32 r = (u + 0x7FFFu + ((u >> 16) & 1u)) >> 16;  // RNE
  return (u16)r;
}

static __device__ __forceinline__ bf16x8 ld16(const u16* p) {
  return __builtin_bit_cast(bf16x8, *(const uint4*)p);
}

static __device__ __forceinline__ u64 u64min(u64 a, u64 b) { return a < b ? a : b; }

// In-wave bitonic sort of 64 u64 keys, ascending by lane.
static __device__ __forceinline__ u64 bitonic64(u64 v, int lane) {
#pragma unroll
  for (int k = 2; k <= 64; k <<= 1) {
#pragma unroll
    for (int j = k >> 1; j > 0; j >>= 1) {
      u64 o = __shfl_xor(v, j, 64);
      bool up = ((lane & k) == 0);
      bool lower = ((lane & j) == 0);
      u64 mn = v < o ? v : o;
      u64 mx = v < o ? o : v;
      v = (lower == up) ? mn : mx;
    }
  }
  return v;
}

// In-wave bitonic sort of 64 f32 (no NaN), ascending by lane.
static __device__ __forceinline__ float bitonic64f(float v, int lane) {
#pragma unroll
  for (int k = 2; k <= 64; k <<= 1) {
#pragma unroll
    for (int j = k >> 1; j > 0; j >>= 1) {
      float o = __shfl_xor(v, j, 64);
      bool up = ((lane & k) == 0);
      bool lower = ((lane & j) == 0);
      float mn = fminf(v, o);
      float mx = fmaxf(v, o);
      v = (lower == up) ? mn : mx;
    }
  }
  return v;
}

// monotone u32 key from f32 bits — pure integer transform (safe to duplicate)
static __device__ __forceinline__ u32 fkey(float f) {
  u32 bb = __float_as_uint(f);
  u32 sgn = (u32)((int)bb >> 31);
  return bb ^ (sgn | 0x80000000u);
}

// Reference fp32 distance semantics (matches np, verified r3..r16):
//   dot = fma(z,bz, fma(y,by, mul(x,bx)));  d2 = fl(fl(s1+s2) - fl(2*dot))
static __device__ __forceinline__ float d2of(float x, float y, float z, float s1,
                                             f32x4 c) {
  float dt = __builtin_fmaf(z, c[2], __builtin_fmaf(y, c[1], __fmul_rn(x, c[0])));
  return __fsub_rn(__fadd_rn(s1, c[3]), __fmul_rn(2.0f, dt));
}

// ---------------------------------------------------------------------------
// K1: PREP + KNN-16 in one kernel (verbatim r15 — measured 58.7 µs; r12
// lesson: this shape sits just under LDS/VGPR cliffs, do not add pressure).
// ---------------------------------------------------------------------------
__global__ __launch_bounds__(256, 2) void knn_prep(
    const float* __restrict__ xyz1, const float* __restrict__ xyz2,
    const float* __restrict__ points1, const float* __restrict__ points2,
    const float* __restrict__ W1, const float* __restrict__ W2,
    u16* __restrict__ p1t, u16* __restrict__ p2t,
    u16* __restrict__ W1b, u16* __restrict__ W2b,
    int* __restrict__ knn) {
  __shared__ __align__(16) char LB[65536];
  f32x4* candL = (f32x4*)LB;     // 4096 * 16 B (knn phase)
  u16* tile = (u16*)LB;          // 64*66*2 = 8448 B (transpose phase)
  __shared__ u64 surv[4][64];    // 2 KB
  __shared__ u32 cnt[4];
  const int t = threadIdx.x;
  const int lane = t & 63;
  const int w = t >> 6;
  const int g = blockIdx.x;

  // ---- part 0: W cast (blocks 0..143) ------------------------------------
  if (g < 144) {
    int i = g * 256 + t;
    if (i < 128 * 160) {
      int r = i / 160, c = i - r * 160;
      W1b[i] = (c < 131) ? f2bf(W1[r * 131 + c]) : (u16)0;
    } else {
      int u = i - 128 * 160;
      W2b[u] = f2bf(W2[u]);
    }
  }

  // ---- part 1: one transpose tile per block ------------------------------
  {
    const float* src = (g < 256) ? points1 : points2;
    u16* dst = (g < 256) ? p1t : p2t;
    const int gb = g & 255;
    const int tb = gb >> 6;
    const int n0 = (gb & 63) << 6;
    const float* sp = src + ((size_t)tb << 18);
#pragma unroll
    for (int i = 0; i < 16; i++) {
      int d = (i << 2) + (t >> 6);
      int n = t & 63;
      tile[n * 66 + d] = f2bf(sp[((size_t)d << 12) + n0 + n]);
    }
    __syncthreads();
    u16* dp = dst + ((size_t)(tb * 4096 + n0) << 6);
#pragma unroll
    for (int i = 0; i < 8; i++) {
      int n = (i << 3) + (t >> 5);
      int dp2 = t & 31;
      *(u32*)(dp + n * 64 + (dp2 << 1)) = *(const u32*)(tile + n * 66 + (dp2 << 1));
    }
  }
  __syncthreads();  // tile reads complete before candL overwrites the region

  // ---- part 2: stage candidates; SINGLE site computing s2 (r5 lesson) ----
  const int b = g >> 7;              // 512 blocks: 128 per batch
  const int rbase = (g & 127) << 5;  // 32 rows per block
  const float* X1 = xyz1 + b * 12288;
  const float* X2 = xyz2 + b * 12288;
#pragma unroll
  for (int i = 0; i < 16; i++) {
    int m = i * 256 + t;
    float x = X2[m], y = X2[4096 + m], z = X2[8192 + m];
    float s2 = __fadd_rn(__fadd_rn(__fmul_rn(x, x), __fmul_rn(y, y)),
                         __fmul_rn(z, z));
    f32x4 pk = {x, y, z, s2};
    candL[m] = pk;
  }
  __syncthreads();

  // ---- part 3: KNN (verbatim r13; keys[64] ONE array — r4/r10 lesson) ----
#pragma unroll 1
  for (int r = 0; r < 8; r++) {
    const int n = rbase + (w << 3) + r;
    const int row = b * 4096 + n;
    const float x = X1[n], y = X1[4096 + n], z = X1[8192 + n];
    const float s1 = __fadd_rn(__fadd_rn(__fmul_rn(x, x), __fmul_rn(y, y)),
                               __fmul_rn(z, z));

    float keys[64];
    float fm = 3e38f;
#pragma unroll
    for (int j = 0; j < 64; j++) {
      const int m = (j << 6) + lane;
      f32x4 c = candL[m];
      float d = d2of(x, y, z, s1, c);
      keys[j] = d;
      fm = fminf(fm, d);
    }

    float tauf = __shfl(bitonic64f(fm, lane), 15, 64);

    if (lane == 0) cnt[w] = 0;
#pragma unroll
    for (int j = 0; j < 64; j++) {
      if (keys[j] <= tauf) {
        u64 k64 = ((u64)fkey(keys[j]) << 32) | (u32)((j << 6) + lane);
        u32 slot = atomicAdd(&cnt[w], 1u);
        if (slot < 64) surv[w][slot] = k64;
      }
    }
    u32 S = cnt[w];  // same-wave LDS ops in program order

    if (S <= 64) {
      u64 v = (lane < (int)S) ? surv[w][lane] : ~0ull;
      v = bitonic64(v, lane);
      if (lane < 16) knn[row * 16 + lane] = (int)(v & 0xFFFFFFFFull);
    } else {
      // exact cold path: increasing-order extraction from the register keys
      u64 prev = 0;
      for (int rr = 0; rr < 16; rr++) {
        u64 lm = ~0ull;
#pragma unroll
        for (int j = 0; j < 64; j++) {
          u64 k64 = ((u64)fkey(keys[j]) << 32) | (u32)((j << 6) + lane);
          if (k64 > prev && k64 < lm) lm = k64;
        }
        u64 gm = lm;
#pragma unroll
        for (int off = 32; off; off >>= 1) gm = u64min(gm, __shfl_xor(gm, off, 64));
        if (lane == 0) knn[row * 16 + rr] = (int)(gm & 0xFFFFFFFFull);
        prev = gm;
      }
    }
  }
}

// ---------------------------------------------------------------------------
// K3: fused gather + MLP + weighted reduce (verbatim r9/r13/r15 — measured
// best; r16's 2x2 retile regressed via H1 write conflicts + W L1-thrash).
// Waves split the N-dim: each wave owns 32 output channels, covers all 128
// M-rows; W slice (18 KB) L1-resident; A-fragments shared from LDS.
// ---------------------------------------------------------------------------
__global__ __launch_bounds__(256, 3) void mlp_kernel(
    const float* __restrict__ xyz1, const float* __restrict__ xyz2,
    const u16* __restrict__ p1t, const u16* __restrict__ p2t,
    const int* __restrict__ knn,
    const u16* __restrict__ W1b, const float* __restrict__ b1,
    const u16* __restrict__ W2b, const float* __restrict__ b2,
    float* __restrict__ out) {
  __shared__ __align__(16) u16 F[128 * 168];
  __shared__ __align__(16) float winv[128];
  __shared__ __align__(16) float wnorm[128];
  __shared__ __align__(16) float outbuf[128 * 12];
  const int t = threadIdx.x;
  const int g = blockIdx.x;
  const int b = g >> 9;
  const int rbase = (g & 511) << 3;

  // ---- Phase A: build F = [p1 | p2[idx] | dir | 0-pad] --------------------
  {
    const int m = t >> 1, half = t & 1;
    const int n1 = rbase + (m >> 4);
    const uint4* s1p = (const uint4*)(p1t + ((size_t)(b * 4096 + n1) << 6)) + half * 4;
    uint4* d1p = (uint4*)(F + m * 168) + half * 4;
    d1p[0] = s1p[0]; d1p[1] = s1p[1]; d1p[2] = s1p[2]; d1p[3] = s1p[3];
    const int idx = knn[(((size_t)(b * 4096 + n1)) << 4) + (m & 15)];
    const uint4* s2p = (const uint4*)(p2t + ((size_t)(b * 4096 + idx) << 6)) + half * 4;
    uint4* d2p = (uint4*)(F + m * 168 + 64) + half * 4;
    d2p[0] = s2p[0]; d2p[1] = s2p[1]; d2p[2] = s2p[2]; d2p[3] = s2p[3];
  }
  if (t < 128) {
    const int m = t;
    const int n1 = rbase + (m >> 4);
    const int idx = knn[(((size_t)(b * 4096 + n1)) << 4) + (m & 15)];
    const float* X1 = xyz1 + b * 12288;
    const float* X2 = xyz2 + b * 12288;
    float dx = X2[idx] - X1[n1];
    float dy = X2[4096 + idx] - X1[4096 + n1];
    float dz = X2[8192 + idx] - X1[8192 + n1];
    u32 u0 = (u32)f2bf(dx) | ((u32)f2bf(dy) << 16);
    u32 u1 = (u32)f2bf(dz);
    uint4 pk = make_uint4(u0, u1, 0u, 0u);
    *(uint4*)(F + m * 168 + 128) = pk;
    float d = sqrtf(dx * dx + dy * dy + dz * dz);
    winv[m] = 1.0f / fmaxf(d, 1e-10f);
  } else {
    const int m = t - 128;
    uint4 zz = make_uint4(0u, 0u, 0u, 0u);
    uint4* zp = (uint4*)(F + m * 168 + 136);
    zp[0] = zz; zp[1] = zz; zp[2] = zz; zp[3] = zz;
  }
  __syncthreads();  // barrier 1: F + winv visible

  if (t < 128) {
    const int r = t >> 4;
    float s = 0.f;
#pragma unroll
    for (int k = 0; k < 16; k++) s += winv[(r << 4) + k];
    wnorm[t] = winv[t] / s;
  }

  const int lane = t & 63;
  const int wid = t >> 6;
  const int l15 = lane & 15;
  const int quad = lane >> 4;
  const int koff = quad << 3;
  const int nbase = wid << 5;

  // ---- GEMM1 -------------------------------------------------------------
  f32x4 acc[8][2];
  const f32x4 z4 = {0.f, 0.f, 0.f, 0.f};
#pragma unroll
  for (int i = 0; i < 8; i++)
#pragma unroll
    for (int j = 0; j < 2; j++) acc[i][j] = z4;

#pragma unroll
  for (int s = 0; s < 5; s++) {
    bf16x8 bf0 = ld16(W1b + (nbase + l15) * 160 + s * 32 + koff);
    bf16x8 bf1 = ld16(W1b + (nbase + 16 + l15) * 160 + s * 32 + koff);
#pragma unroll
    for (int mt = 0; mt < 8; mt++) {
      bf16x8 a = ld16(F + (mt * 16 + l15) * 168 + s * 32 + koff);
      acc[mt][0] = MFMA16(a, bf0, acc[mt][0]);
      acc[mt][1] = MFMA16(a, bf1, acc[mt][1]);
    }
  }
  __syncthreads();  // barrier 2: GEMM1 reads done before H1 overwrite

  {
    const float bv0 = b1[nbase + l15];
    const float bv1 = b1[nbase + 16 + l15];
#pragma unroll
    for (int mt = 0; mt < 8; mt++) {
      u16* hrow = F + (mt * 16 + quad * 4) * 168;
#pragma unroll
      for (int r = 0; r < 4; r++) {
        float zv0 = acc[mt][0][r] + bv0;
        zv0 = (zv0 >= 0.f) ? zv0 : 0.1f * zv0;
        hrow[r * 168 + nbase + l15] = f2bf(zv0);
        float zv1 = acc[mt][1][r] + bv1;
        zv1 = (zv1 >= 0.f) ? zv1 : 0.1f * zv1;
        hrow[r * 168 + nbase + 16 + l15] = f2bf(zv1);
      }
    }
  }
  __syncthreads();  // barrier 3: H1 visible

  // ---- GEMM2 -------------------------------------------------------------
  f32x4 acc2[8][2];
#pragma unroll
  for (int i = 0; i < 8; i++)
#pragma unroll
    for (int j = 0; j < 2; j++) acc2[i][j] = z4;

#pragma unroll
  for (int s = 0; s < 4; s++) {
    bf16x8 bf0 = ld16(W2b + (nbase + l15) * 128 + s * 32 + koff);
    bf16x8 bf1 = ld16(W2b + (nbase + 16 + l15) * 128 + s * 32 + koff);
#pragma unroll
    for (int mt = 0; mt < 8; mt++) {
      bf16x8 a = ld16(F + (mt * 16 + l15) * 168 + s * 32 + koff);
      acc2[mt][0] = MFMA16(a, bf0, acc2[mt][0]);
      acc2[mt][1] = MFMA16(a, bf1, acc2[mt][1]);
    }
  }

  {
    const float bv0 = b2[nbase + l15];
    const float bv1 = b2[nbase + 16 + l15];
#pragma unroll
    for (int mt = 0; mt < 8; mt++) {
      const f32x4 w4 = *(const f32x4*)&wnorm[(mt << 4) + (quad << 2)];
      float p0 = 0.f, p1 = 0.f;
#pragma unroll
      for (int r = 0; r < 4; r++) {
        float zv0 = acc2[mt][0][r] + bv0;
        zv0 = (zv0 >= 0.f) ? zv0 : 0.1f * zv0;
        p0 += zv0 * w4[r];
        float zv1 = acc2[mt][1][r] + bv1;
        zv1 = (zv1 >= 0.f) ? zv1 : 0.1f * zv1;
        p1 += zv1 * w4[r];
      }
      p0 += __shfl_xor(p0, 16); p0 += __shfl_xor(p0, 32);
      p1 += __shfl_xor(p1, 16); p1 += __shfl_xor(p1, 32);
      if (quad == 0) {
        outbuf[(nbase + l15) * 12 + mt] = p0;
        outbuf[(nbase + 16 + l15) * 12 + mt] = p1;
      }
    }
  }
  __syncthreads();  // barrier 4: outbuf visible
  {
    const int ch = t >> 1, half = t & 1;
    f32x4 v = *(const f32x4*)&outbuf[ch * 12 + (half << 2)];
    float* op = out + (((size_t)(b * 128 + ch)) << 12) + rbase + (half << 2);
    *(f32x4*)op = v;
  }
}

// ---------------------------------------------------------------------------
extern "C" void kernel_launch(void* const* d_in, const int* in_sizes, int n_in,
                              void* d_out, int out_size, void* d_ws, size_t ws_size,
                              hipStream_t stream) {
  const float* xyz1 = (const float*)d_in[0];
  const float* xyz2 = (const float*)d_in[1];
  const float* points1 = (const float*)d_in[2];
  const float* points2 = (const float*)d_in[3];
  const float* W1 = (const float*)d_in[4];
  const float* b1 = (const float*)d_in[5];
  const float* W2 = (const float*)d_in[6];
  const float* b2 = (const float*)d_in[7];
  float* out = (float*)d_out;

  char* ws = (char*)d_ws;
  int* knn = (int*)ws;                        // 1,048,576 B
  u16* p1t = (u16*)(ws + 1048576);            // 2,097,152 B
  u16* p2t = (u16*)(ws + 3145728);            // 2,097,152 B
  u16* W1b = (u16*)(ws + 5242880);            // 40,960 B
  u16* W2b = (u16*)(ws + 5283840);            // 32,768 B

  hipLaunchKernelGGL(knn_prep, dim3(512), dim3(256), 0, stream,
                     xyz1, xyz2, points1, points2, W1, W2, p1t, p2t, W1b, W2b, knn);
  hipLaunchKernelGGL(mlp_kernel, dim3(2048), dim3(256), 0, stream,
                     xyz1, xyz2, p1t, p2t, knn, W1b, b1, W2b, b2, out);
}